// Round 2
// baseline (210.624 us; speedup 1.0000x reference)
//
#include <hip/hip_runtime.h>
#include <hip/hip_bf16.h>

#define N_NODES 20000
#define BATCH   4
#define F_DIM   256
#define O_DIM   256
#define E_EDGES 160000
#define M_ROWS  (BATCH * N_NODES)   // 80000
#define K_DIM   512                 // concat: X (0..255) | Xagg (256..511)

typedef __bf16 bf16_t;
typedef bf16_t bf16x8 __attribute__((ext_vector_type(8)));
typedef bf16_t bf16x4 __attribute__((ext_vector_type(4)));
typedef float  f32x4  __attribute__((ext_vector_type(4)));

// ---------- K1: fused X->bf16 convert (XCD-pinned) + weight transpose + deg zero ----------
__global__ void __launch_bounds__(256) k_prep(const float* __restrict__ X,
                                              const float* __restrict__ W1,
                                              const float* __restrict__ W2,
                                              bf16_t* __restrict__ A,
                                              bf16_t* __restrict__ Wt,
                                              int* __restrict__ deg) {
    const int bid = blockIdx.x;
    const int tid = threadIdx.x;
    if (bid < 10000) {
        // batch b -> XCDs {2b, 2b+1}; 8 rows per block
        const int xcd = bid & 7, b = xcd >> 1, s = xcd & 1, g = bid >> 3;  // g: 0..1249
        const int row = (s * 1250 + g) * 8 + (tid >> 5);
        const size_t m = (size_t)b * N_NODES + row;
        const int col = (tid & 31) * 8;
        const float4 v0 = *reinterpret_cast<const float4*>(X + m * F_DIM + col);
        const float4 v1 = *reinterpret_cast<const float4*>(X + m * F_DIM + col + 4);
        bf16x8 o = { (bf16_t)v0.x, (bf16_t)v0.y, (bf16_t)v0.z, (bf16_t)v0.w,
                     (bf16_t)v1.x, (bf16_t)v1.y, (bf16_t)v1.z, (bf16_t)v1.w };
        *reinterpret_cast<bf16x8*>(A + m * K_DIM + col) = o;
    } else if (bid < 10512) {
        const int k = bid - 10000;   // 0..511
        const float v = (k < F_DIM) ? W1[(size_t)k * O_DIM + tid]
                                    : W2[(size_t)(k - F_DIM) * O_DIM + tid];
        Wt[(size_t)tid * K_DIM + k] = (bf16_t)v;
    } else {
        const int idx = (bid - 10512) * 256 + tid;
        if (idx < N_NODES) deg[idx] = 0;
    }
}

// ---------- CSR build ----------
__global__ void k_deg(const int* __restrict__ rows, int* __restrict__ deg) {
    int e = blockIdx.x * 256 + threadIdx.x;
    atomicAdd(&deg[rows[e]], 1);
}

__global__ void __launch_bounds__(1024) k_scan(const int* __restrict__ deg,
                                               int* __restrict__ offsets,
                                               int* __restrict__ cursor) {
    __shared__ int wsum[16];
    const int t = threadIdx.x;          // 0..1023
    const int lane = t & 63, wv = t >> 6;
    const int CH = 20;
    int b = t * CH; if (b > N_NODES) b = N_NODES;
    int e = b + CH; if (e > N_NODES) e = N_NODES;
    int s = 0;
    for (int i = b; i < e; ++i) s += deg[i];
    // wave inclusive scan
    int ps = s;
#pragma unroll
    for (int off = 1; off < 64; off <<= 1) {
        int o = __shfl_up(ps, off);
        if (lane >= off) ps += o;
    }
    if (lane == 63) wsum[wv] = ps;
    __syncthreads();
    if (t == 0) {
        int run = 0;
#pragma unroll
        for (int j = 0; j < 16; ++j) { int v = wsum[j]; wsum[j] = run; run += v; }
        offsets[N_NODES] = run;         // == E
    }
    __syncthreads();
    int run = wsum[wv] + (ps - s);      // exclusive prefix for this thread
    for (int i = b; i < e; ++i) {
        offsets[i] = run; cursor[i] = run;
        run += deg[i];
    }
}

__global__ void k_scatter(const int* __restrict__ rows, const int* __restrict__ cols,
                          const float* __restrict__ vals, int* __restrict__ cursor,
                          int* __restrict__ ccol, float* __restrict__ cval) {
    int e = blockIdx.x * 256 + threadIdx.x;
    int r = rows[e];
    int p = atomicAdd(&cursor[r], 1);
    ccol[p] = cols[e];
    cval[p] = vals[e];
}

// ---------- SpMM (XCD-batch-pinned): Xagg[b,n,:] = sum vals*X[b,cols,:] ----------
__global__ void __launch_bounds__(256) k_spmm(const bf16_t* __restrict__ A,
                                              const int* __restrict__ offsets,
                                              const int* __restrict__ ccol,
                                              const float* __restrict__ cval,
                                              bf16_t* __restrict__ Aout) {
    const int bid = blockIdx.x;
    const int xcd = bid & 7;            // dispatch round-robins blockIdx over XCDs
    const int b = xcd >> 1, s = xcd & 1, g = bid >> 3;   // g: 0..2499
    const int w = threadIdx.x >> 6, lane = threadIdx.x & 63;
    const int n = (s * 2500 + g) * 4 + w;                // node, wave-uniform
    const size_t bbase = (size_t)b * N_NODES * K_DIM;
    const int beg = offsets[n], end = offsets[n + 1];
    const bf16_t* Ab = A + bbase + lane * 4;
    float a0 = 0.f, a1 = 0.f, a2 = 0.f, a3 = 0.f;
    int i = beg;
    for (; i + 2 <= end; i += 2) {
        const int c0 = ccol[i], c1 = ccol[i + 1];
        const float v0 = cval[i], v1 = cval[i + 1];
        bf16x4 x0 = *reinterpret_cast<const bf16x4*>(Ab + (size_t)c0 * K_DIM);
        bf16x4 x1 = *reinterpret_cast<const bf16x4*>(Ab + (size_t)c1 * K_DIM);
        a0 += v0 * (float)x0[0] + v1 * (float)x1[0];
        a1 += v0 * (float)x0[1] + v1 * (float)x1[1];
        a2 += v0 * (float)x0[2] + v1 * (float)x1[2];
        a3 += v0 * (float)x0[3] + v1 * (float)x1[3];
    }
    if (i < end) {
        const int c0 = ccol[i];
        const float v0 = cval[i];
        bf16x4 x0 = *reinterpret_cast<const bf16x4*>(Ab + (size_t)c0 * K_DIM);
        a0 += v0 * (float)x0[0]; a1 += v0 * (float)x0[1];
        a2 += v0 * (float)x0[2]; a3 += v0 * (float)x0[3];
    }
    bf16x4 o = { (bf16_t)a0, (bf16_t)a1, (bf16_t)a2, (bf16_t)a3 };
    __builtin_nontemporal_store(o, reinterpret_cast<bf16x4*>(
        Aout + bbase + (size_t)n * K_DIM + F_DIM + lane * 4));
}

// ---------- GEMM: out[m,o] = sum_k A[m,k]*Wt[o,k] + bias[o] ----------
// BM=BN=128, BK=32, double-buffered LDS (32KB -> 5 blocks/CU), 2-phase prefetch,
// XOR-swizzled LDS (chunk ^= (row>>1)&3; inverse applied on global source).
#define GLOAD_LDS16(gptr, lptr)                                                  \
    __builtin_amdgcn_global_load_lds(                                            \
        (const __attribute__((address_space(1))) unsigned int*)(gptr),           \
        (__attribute__((address_space(3))) unsigned int*)(lptr), 16, 0, 0)

__global__ void __launch_bounds__(256, 5) k_gemm(const bf16_t* __restrict__ A,   // [M][512]
                                                 const bf16_t* __restrict__ Bt,  // [256][512]
                                                 const float* __restrict__ bias,
                                                 float* __restrict__ out) {      // [M][256]
    __shared__ bf16_t As[2 * 128 * 32];
    __shared__ bf16_t Bs[2 * 128 * 32];

    const int bid = blockIdx.x;
    const int tile_m = (bid >> 1) * 128;
    const int tile_n = (bid & 1) * 128;
    const int tid = threadIdx.x;
    const int lane = tid & 63;
    const int w = tid >> 6;
    const int wm = (w >> 1) * 64;
    const int wn = (w & 1) * 64;

    // staging: tile = 512 chunks of 16B; thread handles chunks {tid, 256+tid}
    // chunk c -> row c>>2; source k-chunk = (c&3) ^ ((row>>1)&3)  (swizzle involution)
    const int r0 = tid >> 2;                                  // 0..63
    const int kc = (((tid & 3) ^ ((tid >> 3) & 3)) << 3);     // bf16 elems
    const bf16_t* gA0 = A + (size_t)(tile_m + r0) * K_DIM + kc;
    const bf16_t* gA1 = A + (size_t)(tile_m + r0 + 64) * K_DIM + kc;
    const bf16_t* gB0 = Bt + (size_t)(tile_n + r0) * K_DIM + kc;
    const bf16_t* gB1 = Bt + (size_t)(tile_n + r0 + 64) * K_DIM + kc;

    // compute-side read offsets: chunk' = (lane>>4) ^ ((lane>>1)&3)
    const int chrd = (((lane >> 4) ^ ((lane >> 1) & 3)) << 3);
    const int arow = wm + (lane & 15);
    const int brow = wn + (lane & 15);

    f32x4 acc[4][4];
#pragma unroll
    for (int i = 0; i < 4; ++i)
#pragma unroll
        for (int j = 0; j < 4; ++j) acc[i][j] = (f32x4){0.f, 0.f, 0.f, 0.f};

    auto STAGE = [&](int buf, int t) {
        const int ko = t * 32;
        const int lb = buf * 4096;
        GLOAD_LDS16(gA0 + ko, &As[lb + tid * 8]);
        GLOAD_LDS16(gA1 + ko, &As[lb + (256 + tid) * 8]);
        GLOAD_LDS16(gB0 + ko, &Bs[lb + tid * 8]);
        GLOAD_LDS16(gB1 + ko, &Bs[lb + (256 + tid) * 8]);
    };
    auto COMPUTE = [&](int buf) {
        const bf16_t* a = &As[buf * 4096];
        const bf16_t* bb = &Bs[buf * 4096];
        bf16x8 af[4];
#pragma unroll
        for (int i = 0; i < 4; ++i)
            af[i] = *reinterpret_cast<const bf16x8*>(a + (arow + i * 16) * 32 + chrd);
#pragma unroll
        for (int j = 0; j < 4; ++j) {
            bf16x8 bf = *reinterpret_cast<const bf16x8*>(bb + (brow + j * 16) * 32 + chrd);
#pragma unroll
            for (int i = 0; i < 4; ++i)
                acc[i][j] = __builtin_amdgcn_mfma_f32_16x16x32_bf16(af[i], bf, acc[i][j], 0, 0, 0);
        }
    };

    STAGE(0, 0);
    __syncthreads();
#pragma unroll
    for (int t = 0; t < 16; t += 2) {
        STAGE(1, t + 1);
        COMPUTE(0);
        __syncthreads();                 // drains vmcnt(0)+lgkmcnt(0)
        if (t + 2 < 16) STAGE(0, t + 2);
        COMPUTE(1);
        __syncthreads();
    }

    // epilogue: C/D layout col=lane&15, row=(lane>>4)*4+r; nontemporal f32 stores
#pragma unroll
    for (int j = 0; j < 4; ++j) {
        const int col = tile_n + wn + j * 16 + (lane & 15);
        const float bv = bias[col];
#pragma unroll
        for (int i = 0; i < 4; ++i) {
            const int row0 = tile_m + wm + i * 16 + ((lane >> 4) << 2);
#pragma unroll
            for (int r = 0; r < 4; ++r)
                __builtin_nontemporal_store(acc[i][j][r] + bv,
                                            out + (size_t)(row0 + r) * O_DIM + col);
        }
    }
}

extern "C" void kernel_launch(void* const* d_in, const int* in_sizes, int n_in,
                              void* d_out, int out_size, void* d_ws, size_t ws_size,
                              hipStream_t stream) {
    const float* X    = (const float*)d_in[0];
    const int*   rows = (const int*)d_in[1];
    const int*   cols = (const int*)d_in[2];
    const float* vals = (const float*)d_in[3];
    const float* W1   = (const float*)d_in[4];
    const float* W2   = (const float*)d_in[5];
    const float* bias = (const float*)d_in[6];
    float* out = (float*)d_out;

    char* ws = (char*)d_ws;
    size_t off = 0;
    bf16_t* Abuf = (bf16_t*)(ws + off); off += (size_t)M_ROWS * K_DIM * 2;
    bf16_t* Wt   = (bf16_t*)(ws + off); off += (size_t)O_DIM * K_DIM * 2;
    int* deg     = (int*)(ws + off);    off += (size_t)N_NODES * 4;
    int* offsets = (int*)(ws + off);    off += (size_t)(N_NODES + 1) * 4;
    int* cursor  = (int*)(ws + off);    off += (size_t)N_NODES * 4;
    off = (off + 15) & ~(size_t)15;
    int*   ccol  = (int*)(ws + off);    off += (size_t)E_EDGES * 4;
    float* cval  = (float*)(ws + off);  off += (size_t)E_EDGES * 4;

    k_prep<<<10591, 256, 0, stream>>>(X, W1, W2, Abuf, Wt, deg);
    k_deg<<<E_EDGES / 256, 256, 0, stream>>>(rows, deg);
    k_scan<<<1, 1024, 0, stream>>>(deg, offsets, cursor);
    k_scatter<<<E_EDGES / 256, 256, 0, stream>>>(rows, cols, vals, cursor, ccol, cval);
    k_spmm<<<N_NODES, 256, 0, stream>>>(Abuf, offsets, ccol, cval, Abuf);
    k_gemm<<<(M_ROWS / 128) * (O_DIM / 128), 256, 0, stream>>>(Abuf, Wt, bias, out);
}

// Round 4
// 204.228 us; speedup vs baseline: 1.0313x; 1.0313x over previous
//
#include <hip/hip_runtime.h>
#include <hip/hip_bf16.h>

#define N_NODES 20000
#define BATCH   4
#define F_DIM   256
#define O_DIM   256
#define E_EDGES 160000
#define M_ROWS  (BATCH * N_NODES)   // 80000
#define K_DIM   512                 // concat: X (0..255) | Xagg (256..511)
// A-buffer row m = n*BATCH + b  (batch-interleaved so one edge's 4 gathers share a 4KB span)

typedef __bf16 bf16_t;
typedef bf16_t bf16x8 __attribute__((ext_vector_type(8)));
typedef bf16_t bf16x4 __attribute__((ext_vector_type(4)));
typedef float  f32x4  __attribute__((ext_vector_type(4)));

// ---------- K1: fused X->bf16 convert (interleaved layout) + weight transpose + deg zero ----------
__global__ void __launch_bounds__(256) k_prep(const float* __restrict__ X,
                                              const float* __restrict__ W1,
                                              const float* __restrict__ W2,
                                              bf16_t* __restrict__ A,
                                              bf16_t* __restrict__ Wt,
                                              int* __restrict__ deg) {
    const int bid = blockIdx.x;
    const int tid = threadIdx.x;
    if (bid < 10000) {
        const int m = bid * 8 + (tid >> 5);      // m = n*4 + b
        const int n = m >> 2, b = m & 3;
        const int col = (tid & 31) * 8;
        const float* src = X + ((size_t)b * N_NODES + n) * F_DIM + col;
        const float4 v0 = *reinterpret_cast<const float4*>(src);
        const float4 v1 = *reinterpret_cast<const float4*>(src + 4);
        bf16x8 o = { (bf16_t)v0.x, (bf16_t)v0.y, (bf16_t)v0.z, (bf16_t)v0.w,
                     (bf16_t)v1.x, (bf16_t)v1.y, (bf16_t)v1.z, (bf16_t)v1.w };
        *reinterpret_cast<bf16x8*>(A + (size_t)m * K_DIM + col) = o;
    } else if (bid < 10512) {
        const int k = bid - 10000;   // 0..511
        const float v = (k < F_DIM) ? W1[(size_t)k * O_DIM + tid]
                                    : W2[(size_t)(k - F_DIM) * O_DIM + tid];
        Wt[(size_t)tid * K_DIM + k] = (bf16_t)v;
    } else {
        const int idx = (bid - 10512) * 256 + tid;
        if (idx < N_NODES) deg[idx] = 0;
    }
}

// ---------- CSR build ----------
__global__ void k_deg(const int* __restrict__ rows, int* __restrict__ deg) {
    int e = blockIdx.x * 256 + threadIdx.x;
    atomicAdd(&deg[rows[e]], 1);
}

__global__ void __launch_bounds__(1024) k_scan(const int* __restrict__ deg,
                                               int* __restrict__ offsets,
                                               int* __restrict__ cursor) {
    __shared__ int wsum[16];
    const int t = threadIdx.x;          // 0..1023
    const int lane = t & 63, wv = t >> 6;
    const int CH = 20;
    int b = t * CH; if (b > N_NODES) b = N_NODES;
    int e = b + CH; if (e > N_NODES) e = N_NODES;
    int s = 0;
    for (int i = b; i < e; ++i) s += deg[i];
    int ps = s;
#pragma unroll
    for (int off = 1; off < 64; off <<= 1) {
        int o = __shfl_up(ps, off);
        if (lane >= off) ps += o;
    }
    if (lane == 63) wsum[wv] = ps;
    __syncthreads();
    if (t == 0) {
        int run = 0;
#pragma unroll
        for (int j = 0; j < 16; ++j) { int v = wsum[j]; wsum[j] = run; run += v; }
        offsets[N_NODES] = run;         // == E
    }
    __syncthreads();
    int run = wsum[wv] + (ps - s);
    for (int i = b; i < e; ++i) {
        offsets[i] = run; cursor[i] = run;
        run += deg[i];
    }
}

__global__ void k_scatter(const int* __restrict__ rows, const int* __restrict__ cols,
                          const float* __restrict__ vals, int* __restrict__ cursor,
                          int* __restrict__ ccol, float* __restrict__ cval) {
    int e = blockIdx.x * 256 + threadIdx.x;
    int r = rows[e];
    int p = atomicAdd(&cursor[r], 1);
    ccol[p] = cols[e];
    cval[p] = vals[e];
}

// ---------- SpMM: Xagg[m=n*4+b, :] = sum_e vals*A[c*4+b, 0:256] ----------
__global__ void __launch_bounds__(256) k_spmm(const bf16_t* __restrict__ A,
                                              const int* __restrict__ offsets,
                                              const int* __restrict__ ccol,
                                              const float* __restrict__ cval,
                                              bf16_t* __restrict__ Aout) {
    const int n = blockIdx.x;
    const int w = threadIdx.x >> 6, lane = threadIdx.x & 63;   // wave = batch
    const int beg = offsets[n], end = offsets[n + 1];
    const bf16_t* Ab = A + (size_t)w * K_DIM + lane * 4;       // + c*4*K_DIM per edge
    f32x4 acc = {0.f, 0.f, 0.f, 0.f};
    int i = beg;
    for (; i + 4 <= end; i += 4) {
        const int c0 = ccol[i], c1 = ccol[i+1], c2 = ccol[i+2], c3 = ccol[i+3];
        const float v0 = cval[i], v1 = cval[i+1], v2 = cval[i+2], v3 = cval[i+3];
        bf16x4 x0 = *reinterpret_cast<const bf16x4*>(Ab + (size_t)c0 * (4 * K_DIM));
        bf16x4 x1 = *reinterpret_cast<const bf16x4*>(Ab + (size_t)c1 * (4 * K_DIM));
        bf16x4 x2 = *reinterpret_cast<const bf16x4*>(Ab + (size_t)c2 * (4 * K_DIM));
        bf16x4 x3 = *reinterpret_cast<const bf16x4*>(Ab + (size_t)c3 * (4 * K_DIM));
#pragma unroll
        for (int j = 0; j < 4; ++j)
            acc[j] += v0 * (float)x0[j] + v1 * (float)x1[j]
                    + v2 * (float)x2[j] + v3 * (float)x3[j];
    }
    for (; i < end; ++i) {
        const int c0 = ccol[i];
        const float v0 = cval[i];
        bf16x4 x0 = *reinterpret_cast<const bf16x4*>(Ab + (size_t)c0 * (4 * K_DIM));
#pragma unroll
        for (int j = 0; j < 4; ++j) acc[j] += v0 * (float)x0[j];
    }
    bf16x4 o = { (bf16_t)acc[0], (bf16_t)acc[1], (bf16_t)acc[2], (bf16_t)acc[3] };
    // PLAIN store: NT store here broke coherence (bypasses L2 without invalidating;
    // post-poison replays read stale 0xAA L2 lines in k_gemm -> round-3 failure)
    *reinterpret_cast<bf16x4*>(
        Aout + ((size_t)n * 4 + w) * K_DIM + F_DIM + lane * 4) = o;
}

// ---------- GEMM: out[(m&3)*N + (m>>2), o] = sum_k A[m,k]*Wt[o,k] + bias[o] ----------
#define GLOAD_LDS16(gptr, lptr)                                                  \
    __builtin_amdgcn_global_load_lds(                                            \
        (const __attribute__((address_space(1))) unsigned int*)(gptr),           \
        (__attribute__((address_space(3))) unsigned int*)(lptr), 16, 0, 0)

__global__ void __launch_bounds__(256, 5) k_gemm(const bf16_t* __restrict__ A,   // [M][512]
                                                 const bf16_t* __restrict__ Bt,  // [256][512]
                                                 const float* __restrict__ bias,
                                                 float* __restrict__ out) {      // [B*N][256]
    __shared__ bf16_t As[2 * 128 * 32];
    __shared__ bf16_t Bs[2 * 128 * 32];

    const int bid = blockIdx.x;
    const int tile_m = (bid >> 1) * 128;
    const int tile_n = (bid & 1) * 128;
    const int tid = threadIdx.x;
    const int lane = tid & 63;
    const int w = tid >> 6;
    const int wm = (w >> 1) * 64;
    const int wn = (w & 1) * 64;

    // staging swizzle: chunk-in-row ^= (row>>1)&3, applied on the global source
    const int r0 = tid >> 2;                                  // 0..63
    const int kc = (((tid & 3) ^ ((tid >> 3) & 3)) << 3);     // bf16 elems
    const bf16_t* gA0 = A + (size_t)(tile_m + r0) * K_DIM + kc;
    const bf16_t* gA1 = A + (size_t)(tile_m + r0 + 64) * K_DIM + kc;
    const bf16_t* gB0 = Bt + (size_t)(tile_n + r0) * K_DIM + kc;
    const bf16_t* gB1 = Bt + (size_t)(tile_n + r0 + 64) * K_DIM + kc;

    // read-side: logical k-chunk (lane>>4), stored at ^((row>>1)&3)
    const int chrd = (((lane >> 4) ^ ((lane >> 1) & 3)) << 3);
    const int arow = wm + (lane & 15);
    const int brow = wn + (lane & 15);

    f32x4 acc[4][4];
#pragma unroll
    for (int i = 0; i < 4; ++i)
#pragma unroll
        for (int j = 0; j < 4; ++j) acc[i][j] = (f32x4){0.f, 0.f, 0.f, 0.f};

    auto STAGE = [&](int buf, int t) {
        const int ko = t * 32;
        const int lb = buf * 4096;
        GLOAD_LDS16(gA0 + ko, &As[lb + tid * 8]);
        GLOAD_LDS16(gA1 + ko, &As[lb + (256 + tid) * 8]);
        GLOAD_LDS16(gB0 + ko, &Bs[lb + tid * 8]);
        GLOAD_LDS16(gB1 + ko, &Bs[lb + (256 + tid) * 8]);
    };
    auto COMPUTE = [&](int buf) {
        const bf16_t* a = &As[buf * 4096];
        const bf16_t* bb = &Bs[buf * 4096];
        bf16x8 af[4];
#pragma unroll
        for (int i = 0; i < 4; ++i)
            af[i] = *reinterpret_cast<const bf16x8*>(a + (arow + i * 16) * 32 + chrd);
#pragma unroll
        for (int j = 0; j < 4; ++j) {
            bf16x8 bf = *reinterpret_cast<const bf16x8*>(bb + (brow + j * 16) * 32 + chrd);
#pragma unroll
            for (int i = 0; i < 4; ++i)
                acc[i][j] = __builtin_amdgcn_mfma_f32_16x16x32_bf16(af[i], bf, acc[i][j], 0, 0, 0);
        }
    };

    STAGE(0, 0);
    __syncthreads();
#pragma unroll
    for (int t = 0; t < 16; t += 2) {
        STAGE(1, t + 1);
        COMPUTE(0);
        __syncthreads();
        if (t + 2 < 16) STAGE(0, t + 2);
        COMPUTE(1);
        __syncthreads();
    }

    // epilogue: C/D layout col=lane&15, row=(lane>>4)*4+r; plain stores
#pragma unroll
    for (int j = 0; j < 4; ++j) {
        const int col = tile_n + wn + j * 16 + (lane & 15);
        const float bv = bias[col];
#pragma unroll
        for (int i = 0; i < 4; ++i) {
            const int m0 = tile_m + wm + i * 16 + ((lane >> 4) << 2);
#pragma unroll
            for (int r = 0; r < 4; ++r) {
                const int m = m0 + r;                       // m = n*4 + b
                const size_t orow = (size_t)(m & 3) * N_NODES + (m >> 2);
                out[orow * O_DIM + col] = acc[i][j][r] + bv;
            }
        }
    }
}

extern "C" void kernel_launch(void* const* d_in, const int* in_sizes, int n_in,
                              void* d_out, int out_size, void* d_ws, size_t ws_size,
                              hipStream_t stream) {
    const float* X    = (const float*)d_in[0];
    const int*   rows = (const int*)d_in[1];
    const int*   cols = (const int*)d_in[2];
    const float* vals = (const float*)d_in[3];
    const float* W1   = (const float*)d_in[4];
    const float* W2   = (const float*)d_in[5];
    const float* bias = (const float*)d_in[6];
    float* out = (float*)d_out;

    char* ws = (char*)d_ws;
    size_t off = 0;
    bf16_t* Abuf = (bf16_t*)(ws + off); off += (size_t)M_ROWS * K_DIM * 2;
    bf16_t* Wt   = (bf16_t*)(ws + off); off += (size_t)O_DIM * K_DIM * 2;
    int* deg     = (int*)(ws + off);    off += (size_t)N_NODES * 4;
    int* offsets = (int*)(ws + off);    off += (size_t)(N_NODES + 1) * 4;
    int* cursor  = (int*)(ws + off);    off += (size_t)N_NODES * 4;
    off = (off + 15) & ~(size_t)15;
    int*   ccol  = (int*)(ws + off);    off += (size_t)E_EDGES * 4;
    float* cval  = (float*)(ws + off);  off += (size_t)E_EDGES * 4;

    k_prep<<<10591, 256, 0, stream>>>(X, W1, W2, Abuf, Wt, deg);
    k_deg<<<E_EDGES / 256, 256, 0, stream>>>(rows, deg);
    k_scan<<<1, 1024, 0, stream>>>(deg, offsets, cursor);
    k_scatter<<<E_EDGES / 256, 256, 0, stream>>>(rows, cols, vals, cursor, ccol, cval);
    k_spmm<<<N_NODES, 256, 0, stream>>>(Abuf, offsets, ccol, cval, Abuf);
    k_gemm<<<(M_ROWS / 128) * (O_DIM / 128), 256, 0, stream>>>(Abuf, Wt, bias, out);
}

// Round 5
// 157.581 us; speedup vs baseline: 1.3366x; 1.2960x over previous
//
#include <hip/hip_runtime.h>
#include <hip/hip_bf16.h>

#define N_NODES 20000
#define BATCH   4
#define F_DIM   256
#define O_DIM   256
#define E_EDGES 160000
#define M_ROWS  (BATCH * N_NODES)   // 80000
#define K_DIM   512                 // concat: X (0..255) | Xagg (256..511)
// A-buffer row m = n*BATCH + b  (batch-interleaved so one edge's 4 gathers share a 4KB span)

typedef __bf16 bf16_t;
typedef bf16_t bf16x8 __attribute__((ext_vector_type(8)));
typedef bf16_t bf16x4 __attribute__((ext_vector_type(4)));
typedef float  f32x4  __attribute__((ext_vector_type(4)));

// ---------- K1: fused X->bf16 convert (interleaved layout) + weight transpose + deg zero ----------
__global__ void __launch_bounds__(256) k_prep(const float* __restrict__ X,
                                              const float* __restrict__ W1,
                                              const float* __restrict__ W2,
                                              bf16_t* __restrict__ A,
                                              bf16_t* __restrict__ Wt,
                                              int* __restrict__ deg) {
    const int bid = blockIdx.x;
    const int tid = threadIdx.x;
    if (bid < 10000) {
        const int m = bid * 8 + (tid >> 5);      // m = n*4 + b
        const int n = m >> 2, b = m & 3;
        const int col = (tid & 31) * 8;
        const float* src = X + ((size_t)b * N_NODES + n) * F_DIM + col;
        const float4 v0 = *reinterpret_cast<const float4*>(src);
        const float4 v1 = *reinterpret_cast<const float4*>(src + 4);
        bf16x8 o = { (bf16_t)v0.x, (bf16_t)v0.y, (bf16_t)v0.z, (bf16_t)v0.w,
                     (bf16_t)v1.x, (bf16_t)v1.y, (bf16_t)v1.z, (bf16_t)v1.w };
        *reinterpret_cast<bf16x8*>(A + (size_t)m * K_DIM + col) = o;
    } else if (bid < 10512) {
        const int k = bid - 10000;   // 0..511
        const float v = (k < F_DIM) ? W1[(size_t)k * O_DIM + tid]
                                    : W2[(size_t)(k - F_DIM) * O_DIM + tid];
        Wt[(size_t)tid * K_DIM + k] = (bf16_t)v;
    } else {
        const int idx = (bid - 10512) * 256 + tid;
        if (idx < N_NODES) deg[idx] = 0;
    }
}

// ---------- CSR build ----------
__global__ void k_deg(const int* __restrict__ rows, int* __restrict__ deg) {
    int e = blockIdx.x * 256 + threadIdx.x;
    atomicAdd(&deg[rows[e]], 1);
}

__global__ void __launch_bounds__(1024) k_scan(const int* __restrict__ deg,
                                               int* __restrict__ offsets,
                                               int* __restrict__ cursor) {
    __shared__ int wsum[16];
    const int t = threadIdx.x;          // 0..1023
    const int lane = t & 63, wv = t >> 6;
    const int CH = 20;
    int b = t * CH; if (b > N_NODES) b = N_NODES;
    int e = b + CH; if (e > N_NODES) e = N_NODES;
    int s = 0;
    for (int i = b; i < e; ++i) s += deg[i];
    int ps = s;
#pragma unroll
    for (int off = 1; off < 64; off <<= 1) {
        int o = __shfl_up(ps, off);
        if (lane >= off) ps += o;
    }
    if (lane == 63) wsum[wv] = ps;
    __syncthreads();
    if (t == 0) {
        int run = 0;
#pragma unroll
        for (int j = 0; j < 16; ++j) { int v = wsum[j]; wsum[j] = run; run += v; }
        offsets[N_NODES] = run;         // == E
    }
    __syncthreads();
    int run = wsum[wv] + (ps - s);
    for (int i = b; i < e; ++i) {
        offsets[i] = run; cursor[i] = run;
        run += deg[i];
    }
}

__global__ void k_scatter(const int* __restrict__ rows, const int* __restrict__ cols,
                          const float* __restrict__ vals, int* __restrict__ cursor,
                          int* __restrict__ ccol, float* __restrict__ cval) {
    int e = blockIdx.x * 256 + threadIdx.x;
    int r = rows[e];
    int p = atomicAdd(&cursor[r], 1);
    ccol[p] = cols[e];
    cval[p] = vals[e];
}

// ---------- SpMM: Xagg[m=n*4+b, :] = sum_e vals*A[c*4+b, 0:256] ----------
__global__ void __launch_bounds__(256) k_spmm(const bf16_t* __restrict__ A,
                                              const int* __restrict__ offsets,
                                              const int* __restrict__ ccol,
                                              const float* __restrict__ cval,
                                              bf16_t* __restrict__ Aout) {
    const int n = blockIdx.x;
    const int w = threadIdx.x >> 6, lane = threadIdx.x & 63;   // wave = batch
    const int beg = offsets[n], end = offsets[n + 1];
    const bf16_t* Ab = A + (size_t)w * K_DIM + lane * 4;       // + c*4*K_DIM per edge
    f32x4 acc = {0.f, 0.f, 0.f, 0.f};
    int i = beg;
    for (; i + 4 <= end; i += 4) {
        const int c0 = ccol[i], c1 = ccol[i+1], c2 = ccol[i+2], c3 = ccol[i+3];
        const float v0 = cval[i], v1 = cval[i+1], v2 = cval[i+2], v3 = cval[i+3];
        bf16x4 x0 = *reinterpret_cast<const bf16x4*>(Ab + (size_t)c0 * (4 * K_DIM));
        bf16x4 x1 = *reinterpret_cast<const bf16x4*>(Ab + (size_t)c1 * (4 * K_DIM));
        bf16x4 x2 = *reinterpret_cast<const bf16x4*>(Ab + (size_t)c2 * (4 * K_DIM));
        bf16x4 x3 = *reinterpret_cast<const bf16x4*>(Ab + (size_t)c3 * (4 * K_DIM));
#pragma unroll
        for (int j = 0; j < 4; ++j)
            acc[j] += v0 * (float)x0[j] + v1 * (float)x1[j]
                    + v2 * (float)x2[j] + v3 * (float)x3[j];
    }
    for (; i < end; ++i) {
        const int c0 = ccol[i];
        const float v0 = cval[i];
        bf16x4 x0 = *reinterpret_cast<const bf16x4*>(Ab + (size_t)c0 * (4 * K_DIM));
#pragma unroll
        for (int j = 0; j < 4; ++j) acc[j] += v0 * (float)x0[j];
    }
    bf16x4 o = { (bf16_t)acc[0], (bf16_t)acc[1], (bf16_t)acc[2], (bf16_t)acc[3] };
    *reinterpret_cast<bf16x4*>(
        Aout + ((size_t)n * 4 + w) * K_DIM + F_DIM + lane * 4) = o;
}

// ---------- GEMM: out[(m&3)*N + (m>>2), o] = sum_k A[m,k]*Wt[o,k] + bias[o] ----------
// BM=BN=128, BK=64 (full 128B-line staging), double-buffered (64KB LDS, 2 blk/CU),
// XOR swizzle chunk^=row&7 (global-source side), bijective XCD pairing of n-tiles.
#define GLOAD_LDS16(gptr, lptr)                                                  \
    __builtin_amdgcn_global_load_lds(                                            \
        (const __attribute__((address_space(1))) unsigned int*)(gptr),           \
        (__attribute__((address_space(3))) unsigned int*)(lptr), 16, 0, 0)

__global__ void __launch_bounds__(256, 2) k_gemm(const bf16_t* __restrict__ A,   // [M][512]
                                                 const bf16_t* __restrict__ Bt,  // [256][512]
                                                 const float* __restrict__ bias,
                                                 float* __restrict__ out) {      // [B*N][256]
    __shared__ bf16_t As[2 * 128 * 64];   // 32 KB
    __shared__ bf16_t Bs[2 * 128 * 64];   // 32 KB

    // bijective XCD chunking: 1250 blocks, xcd 0,1 -> 157 serials, 2..7 -> 156.
    // consecutive serials (the two n-tiles of an m-tile, then next m-tile) stay
    // on one XCD -> A-panel re-read hits that XCD's L2.
    const int b0 = blockIdx.x;
    const int xcd = b0 & 7, idx = b0 >> 3;
    const int serial = (xcd < 2 ? xcd * 157 : 314 + (xcd - 2) * 156) + idx;
    const int tile_m = (serial >> 1) * 128;
    const int tile_n = (serial & 1) * 128;

    const int tid = threadIdx.x;
    const int lane = tid & 63;
    const int w = tid >> 6;
    const int wm = (w >> 1) * 64;
    const int wn = (w & 1) * 64;

    f32x4 acc[4][4];
#pragma unroll
    for (int i = 0; i < 4; ++i)
#pragma unroll
        for (int j = 0; j < 4; ++j) acc[i][j] = (f32x4){0.f, 0.f, 0.f, 0.f};

    // staging: tile = 1024 chunks of 16B ([128 rows][8 chunks]); LDS linear in chunk
    // order => LDS[row][c] = A[row][c ^ (row&7)] (swizzle applied on global source)
    auto STAGE = [&](int buf, int t) {
        const int k0 = t * 64;
#pragma unroll
        for (int r = 0; r < 4; ++r) {
            const int c = r * 256 + tid;           // 0..1023
            const int row = c >> 3;
            const int sc = (c & 7) ^ (row & 7);    // source 16B-chunk in row
            GLOAD_LDS16(A  + (size_t)(tile_m + row) * K_DIM + k0 + sc * 8,
                        &As[buf * 8192 + c * 8]);
            GLOAD_LDS16(Bt + (size_t)(tile_n + row) * K_DIM + k0 + sc * 8,
                        &Bs[buf * 8192 + c * 8]);
        }
    };
    auto COMPUTE = [&](int buf) {
        const bf16_t* a  = &As[buf * 8192];
        const bf16_t* bb = &Bs[buf * 8192];
#pragma unroll
        for (int ks = 0; ks < 2; ++ks) {
            // logical chunk (ks*4 + lane>>4), stored at ^(row&7); row&7 == lane&7
            const int ch = ((((ks << 2) | (lane >> 4)) ^ (lane & 7)) << 3);
            bf16x8 af[4];
#pragma unroll
            for (int i = 0; i < 4; ++i)
                af[i] = *reinterpret_cast<const bf16x8*>(a + (wm + i * 16 + (lane & 15)) * 64 + ch);
#pragma unroll
            for (int j = 0; j < 4; ++j) {
                bf16x8 bfr = *reinterpret_cast<const bf16x8*>(bb + (wn + j * 16 + (lane & 15)) * 64 + ch);
#pragma unroll
                for (int i = 0; i < 4; ++i)
                    acc[i][j] = __builtin_amdgcn_mfma_f32_16x16x32_bf16(af[i], bfr, acc[i][j], 0, 0, 0);
            }
        }
    };

    STAGE(0, 0);
    __syncthreads();
#pragma unroll
    for (int t = 0; t < 8; t += 2) {
        STAGE(1, t + 1);
        COMPUTE(0);
        __syncthreads();
        if (t + 2 < 8) STAGE(0, t + 2);
        COMPUTE(1);
        __syncthreads();
    }

    // epilogue: C/D layout col=lane&15, row=(lane>>4)*4+r; plain stores
#pragma unroll
    for (int j = 0; j < 4; ++j) {
        const int col = tile_n + wn + j * 16 + (lane & 15);
        const float bv = bias[col];
#pragma unroll
        for (int i = 0; i < 4; ++i) {
            const int m0 = tile_m + wm + i * 16 + ((lane >> 4) << 2);
#pragma unroll
            for (int r = 0; r < 4; ++r) {
                const int m = m0 + r;                       // m = n*4 + b
                const size_t orow = (size_t)(m & 3) * N_NODES + (m >> 2);
                out[orow * O_DIM + col] = acc[i][j][r] + bv;
            }
        }
    }
}

extern "C" void kernel_launch(void* const* d_in, const int* in_sizes, int n_in,
                              void* d_out, int out_size, void* d_ws, size_t ws_size,
                              hipStream_t stream) {
    const float* X    = (const float*)d_in[0];
    const int*   rows = (const int*)d_in[1];
    const int*   cols = (const int*)d_in[2];
    const float* vals = (const float*)d_in[3];
    const float* W1   = (const float*)d_in[4];
    const float* W2   = (const float*)d_in[5];
    const float* bias = (const float*)d_in[6];
    float* out = (float*)d_out;

    char* ws = (char*)d_ws;
    size_t off = 0;
    bf16_t* Abuf = (bf16_t*)(ws + off); off += (size_t)M_ROWS * K_DIM * 2;
    bf16_t* Wt   = (bf16_t*)(ws + off); off += (size_t)O_DIM * K_DIM * 2;
    int* deg     = (int*)(ws + off);    off += (size_t)N_NODES * 4;
    int* offsets = (int*)(ws + off);    off += (size_t)(N_NODES + 1) * 4;
    int* cursor  = (int*)(ws + off);    off += (size_t)N_NODES * 4;
    off = (off + 15) & ~(size_t)15;
    int*   ccol  = (int*)(ws + off);    off += (size_t)E_EDGES * 4;
    float* cval  = (float*)(ws + off);  off += (size_t)E_EDGES * 4;

    k_prep<<<10591, 256, 0, stream>>>(X, W1, W2, Abuf, Wt, deg);
    k_deg<<<E_EDGES / 256, 256, 0, stream>>>(rows, deg);
    k_scan<<<1, 1024, 0, stream>>>(deg, offsets, cursor);
    k_scatter<<<E_EDGES / 256, 256, 0, stream>>>(rows, cols, vals, cursor, ccol, cval);
    k_spmm<<<N_NODES, 256, 0, stream>>>(Abuf, offsets, ccol, cval, Abuf);
    k_gemm<<<(M_ROWS / 128) * (O_DIM / 128), 256, 0, stream>>>(Abuf, Wt, bias, out);
}